// Round 3
// baseline (453.372 us; speedup 1.0000x reference)
//
#include <hip/hip_runtime.h>
#include <hip/hip_cooperative_groups.h>

namespace cg = cooperative_groups;

// RandomEqualize: PIL-style histogram equalization per (batch, channel).
// Input: float32 (64,3,512,512), exact integer values in [0,255].
// N = 192 channels, P = 262144 pixels/channel.
//
// Single cooperative kernel, 768 blocks (3/CU co-resident, 34 KB LDS):
//  phase 1: per-block LDS histogram (32 bank-strided copies, ds_add) -> global
//           partials. Input floats get pulled through L2/L3 (201 MB < 256 MB L3).
//  grid.sync()
//  phase 2: each block redundantly reduces its channel's 4 partials -> PIL LUT
//           (scan in LDS, ~2 us), then re-reads ITS OWN input chunk (L3-hit) and
//           applies the 32x bank-replicated LUT; NT float4 stores so the output
//           doesn't evict the input from L3.
// HBM traffic ~= mandatory 201 MB read + 201 MB write (no intermediate).

#define NBINS 256
#define BPC 4                   // blocks per channel
#define CHUNK 65536             // P / BPC pixels per block
#define NVEC (CHUNK / 4)        // float4 packets per block = 16384

typedef float vfloat4 __attribute__((ext_vector_type(4)));

__global__ __launch_bounds__(256) void eq_fused_kernel(
    const float* __restrict__ in, float* __restrict__ out,
    unsigned int* __restrict__ phist, int P) {
    __shared__ unsigned int lh[NBINS * 32];  // 32 KB hist; reused as LUT in phase 2
    __shared__ unsigned int s[NBINS];
    __shared__ int sidx[NBINS];
    const int t = threadIdx.x;
    const int copy = t & 31;
    const int chan = blockIdx.x >> 2;        // BPC = 4

    // ---- phase 1: histogram ----
    for (int i = t; i < NBINS * 32; i += 256) lh[i] = 0u;
    __syncthreads();

    // chan*(CHUNK*BPC) + blk*CHUNK == blockIdx.x*CHUNK
    const size_t basev = ((size_t)blockIdx.x * CHUNK) >> 2;  // float4 units
    const float4* vin = (const float4*)in + basev;

    #pragma unroll 4
    for (int i = t; i < NVEC; i += 256) {
        float4 v = vin[i];
        int ix = min(max((int)v.x, 0), 255);
        int iy = min(max((int)v.y, 0), 255);
        int iz = min(max((int)v.z, 0), 255);
        int iw = min(max((int)v.w, 0), 255);
        atomicAdd(&lh[ix * 32 + copy], 1u);   // bank = copy = lane&31: conflict-free
        atomicAdd(&lh[iy * 32 + copy], 1u);
        atomicAdd(&lh[iz * 32 + copy], 1u);
        atomicAdd(&lh[iw * 32 + copy], 1u);
    }
    __syncthreads();

    // thread t owns bin t; staggered copy index keeps lanes on distinct banks
    unsigned int hsum = 0;
    #pragma unroll
    for (int c = 0; c < 32; ++c) hsum += lh[t * 32 + ((t + c) & 31)];
    phist[(size_t)blockIdx.x * NBINS + t] = hsum;

    cg::this_grid().sync();   // device-scope fence + grid barrier

    // ---- phase 2: reduce partials -> PIL LUT (redundant per block, tiny) ----
    unsigned int h = 0;
    const unsigned int* pb = phist + (size_t)chan * BPC * NBINS;
    #pragma unroll
    for (int b = 0; b < BPC; ++b) h += pb[b * NBINS + t];
    s[t] = h;
    sidx[t] = (h != 0u) ? t : -1;
    __syncthreads();

    // max-reduce: last nonzero bin index
    for (int off = 128; off > 0; off >>= 1) {
        if (t < off) sidx[t] = max(sidx[t], sidx[t + off]);
        __syncthreads();
    }
    const int last_idx = sidx[0];
    const int last_val = (int)s[last_idx];
    const int step = (P - last_val) / 255;

    // Hillis-Steele inclusive scan
    for (int off = 1; off < NBINS; off <<= 1) {
        unsigned int v = (t >= off) ? s[t - off] : 0u;
        __syncthreads();
        s[t] += v;
        __syncthreads();
    }

    float lv;
    if (step == 0) {
        lv = (float)t;   // pass-through: identity LUT
    } else {
        int csp = (t == 0) ? 0 : (int)s[t - 1];
        lv = (float)min(max((csp + (step >> 1)) / step, 0), 255);
    }

    float* slut = (float*)lh;   // reuse hist LDS as 32x bank-replicated LUT
    #pragma unroll
    for (int c = 0; c < 32; ++c)
        slut[t * 32 + ((t + c) & 31)] = lv;   // bank (t+c)&31: 2-way, free
    __syncthreads();

    // ---- apply: re-read own chunk (L3-resident), gather LUT, NT store ----
    vfloat4* vout = (vfloat4*)out + basev;
    #pragma unroll 4
    for (int i = t; i < NVEC; i += 256) {
        float4 v = vin[i];
        vfloat4 r;
        r.x = slut[min(max((int)v.x, 0), 255) * 32 + copy];
        r.y = slut[min(max((int)v.y, 0), 255) * 32 + copy];
        r.z = slut[min(max((int)v.z, 0), 255) * 32 + copy];
        r.w = slut[min(max((int)v.w, 0), 255) * 32 + copy];
        __builtin_nontemporal_store(r, &vout[i]);
    }
}

// ---------- fallback path (only used if cooperative launch errors) ----------
__global__ __launch_bounds__(256) void eq_hist_kernel(
    const float* __restrict__ in, unsigned int* __restrict__ phist) {
    __shared__ unsigned int lh[NBINS * 32];
    const int t = threadIdx.x;
    const int copy = t & 31;
    for (int i = t; i < NBINS * 32; i += 256) lh[i] = 0u;
    __syncthreads();
    const size_t basev = ((size_t)blockIdx.x * CHUNK) >> 2;
    const float4* vin = (const float4*)in + basev;
    #pragma unroll 4
    for (int i = t; i < NVEC; i += 256) {
        float4 v = vin[i];
        atomicAdd(&lh[min(max((int)v.x, 0), 255) * 32 + copy], 1u);
        atomicAdd(&lh[min(max((int)v.y, 0), 255) * 32 + copy], 1u);
        atomicAdd(&lh[min(max((int)v.z, 0), 255) * 32 + copy], 1u);
        atomicAdd(&lh[min(max((int)v.w, 0), 255) * 32 + copy], 1u);
    }
    __syncthreads();
    unsigned int hsum = 0;
    #pragma unroll
    for (int c = 0; c < 32; ++c) hsum += lh[t * 32 + ((t + c) & 31)];
    phist[(size_t)blockIdx.x * NBINS + t] = hsum;
}

__global__ __launch_bounds__(256) void eq_lut_apply_kernel(
    const float* __restrict__ in, const unsigned int* __restrict__ phist,
    float* __restrict__ out, int P) {
    __shared__ float slut[NBINS * 32];
    __shared__ unsigned int s[NBINS];
    __shared__ int sidx[NBINS];
    const int t = threadIdx.x;
    const int copy = t & 31;
    const int chan = blockIdx.x >> 2;

    unsigned int h = 0;
    const unsigned int* pb = phist + (size_t)chan * BPC * NBINS;
    #pragma unroll
    for (int b = 0; b < BPC; ++b) h += pb[b * NBINS + t];
    s[t] = h;
    sidx[t] = (h != 0u) ? t : -1;
    __syncthreads();
    for (int off = 128; off > 0; off >>= 1) {
        if (t < off) sidx[t] = max(sidx[t], sidx[t + off]);
        __syncthreads();
    }
    const int last_idx = sidx[0];
    const int last_val = (int)s[last_idx];
    const int step = (P - last_val) / 255;
    for (int off = 1; off < NBINS; off <<= 1) {
        unsigned int v = (t >= off) ? s[t - off] : 0u;
        __syncthreads();
        s[t] += v;
        __syncthreads();
    }
    float lv;
    if (step == 0) lv = (float)t;
    else {
        int csp = (t == 0) ? 0 : (int)s[t - 1];
        lv = (float)min(max((csp + (step >> 1)) / step, 0), 255);
    }
    #pragma unroll
    for (int c = 0; c < 32; ++c) slut[t * 32 + ((t + c) & 31)] = lv;
    __syncthreads();

    const size_t basev = ((size_t)blockIdx.x * CHUNK) >> 2;
    const float4* vin = (const float4*)in + basev;
    vfloat4* vout = (vfloat4*)out + basev;
    #pragma unroll 4
    for (int i = t; i < NVEC; i += 256) {
        float4 v = vin[i];
        vfloat4 r;
        r.x = slut[min(max((int)v.x, 0), 255) * 32 + copy];
        r.y = slut[min(max((int)v.y, 0), 255) * 32 + copy];
        r.z = slut[min(max((int)v.z, 0), 255) * 32 + copy];
        r.w = slut[min(max((int)v.w, 0), 255) * 32 + copy];
        __builtin_nontemporal_store(r, &vout[i]);
    }
}

extern "C" void kernel_launch(void* const* d_in, const int* in_sizes, int n_in,
                              void* d_out, int out_size, void* d_ws, size_t ws_size,
                              hipStream_t stream) {
    const float* img = (const float*)d_in[0];
    float* out = (float*)d_out;

    const int P = 512 * 512;        // pixels per channel
    const int total = in_sizes[0];  // 64*3*512*512 elements
    const int N = total / P;        // 192 channels

    unsigned int* phist = (unsigned int*)d_ws;   // N*BPC*256 u32 = 768 KB

    int Pv = P;
    void* args[] = {(void*)&img, (void*)&out, (void*)&phist, (void*)&Pv};
    hipError_t err = hipLaunchCooperativeKernel(
        (const void*)eq_fused_kernel, dim3(N * BPC), dim3(256), args, 0, stream);
    if (err != hipSuccess) {
        // fallback: classic 2-kernel path (apply reads float input via L3)
        eq_hist_kernel<<<N * BPC, 256, 0, stream>>>(img, phist);
        eq_lut_apply_kernel<<<N * BPC, 256, 0, stream>>>(img, phist, out, P);
    }
}

// Round 4
// 352.969 us; speedup vs baseline: 1.2844x; 1.2844x over previous
//
#include <hip/hip_runtime.h>

// RandomEqualize: PIL-style histogram equalization per (batch, channel).
// Input: float32 (64,3,512,512), exact integer values in [0,255].
// N = 192 channels, P = 262144 pixels/channel.
//
// 2-kernel pipeline (round-2 structure, K1 re-tuned for occupancy):
//  K1: 16-copy bank-strided LDS histogram (16 KB -> 8 blocks/CU with
//      __launch_bounds__(256,8) = 32 waves/CU for latency hiding), BPC_H=16
//      (3072 blocks). Also packs clamped pixels to u8 (cached stores -> L3).
//  K2: reduce 16 partials -> PIL LUT (scan in LDS) -> 32x bank-replicated
//      LUT gather over the compact u8 stream (50 MB, L3-hit) ; NT float4
//      stores (write-bound floor ~= 201 MB / 6.5 TB/s ~= 31 us).

#define NBINS 256
#define NCOPY 16                  // hist replicas: bank = copy + 16*(bin&1), ~2-way
#define BPC_H 16                  // hist blocks per channel  (3072 blocks)
#define BPC_A 4                   // apply blocks per channel (768 blocks)
#define CHUNK_H 16384             // P / BPC_H pixels
#define CHUNK_A 65536             // P / BPC_A pixels
#define NVEC_H (CHUNK_H / 4)      // 4096 float4 packets per hist block
#define NVEC_A (CHUNK_A / 4)      // 16384 u32 packets per apply block

typedef float vfloat4 __attribute__((ext_vector_type(4)));

// ---------------- K1: histogram + u8 pack ----------------
__global__ __launch_bounds__(256, 8) void eq_hist_pack_kernel(
    const float* __restrict__ in, unsigned int* __restrict__ pack,
    unsigned int* __restrict__ phist) {
    __shared__ unsigned int lh[NBINS * NCOPY];   // 16 KB
    const int t = threadIdx.x;
    const int copy = t & (NCOPY - 1);

    for (int i = t; i < NBINS * NCOPY; i += 256) lh[i] = 0u;
    __syncthreads();

    const size_t basev = (size_t)blockIdx.x * NVEC_H;   // float4 / u32 units
    const float4* vin = (const float4*)in + basev;
    unsigned int* pout = pack + basev;                  // one u32 per 4 pixels

    #pragma unroll 4
    for (int i = t; i < NVEC_H; i += 256) {
        float4 v = vin[i];
        int ix = min(max((int)v.x, 0), 255);
        int iy = min(max((int)v.y, 0), 255);
        int iz = min(max((int)v.z, 0), 255);
        int iw = min(max((int)v.w, 0), 255);
        atomicAdd(&lh[ix * NCOPY + copy], 1u);
        atomicAdd(&lh[iy * NCOPY + copy], 1u);
        atomicAdd(&lh[iz * NCOPY + copy], 1u);
        atomicAdd(&lh[iw * NCOPY + copy], 1u);
        pout[i] = (unsigned)ix | ((unsigned)iy << 8) |
                  ((unsigned)iz << 16) | ((unsigned)iw << 24);
    }
    __syncthreads();

    // thread t owns bin t; staggered copy index keeps lanes ~2/bank (free)
    unsigned int hsum = 0;
    #pragma unroll
    for (int c = 0; c < NCOPY; ++c)
        hsum += lh[t * NCOPY + ((t + c) & (NCOPY - 1))];
    phist[(size_t)blockIdx.x * NBINS + t] = hsum;   // partial, no atomics
}

// ---------------- K2: LUT build + apply ----------------
__global__ __launch_bounds__(256) void eq_lut_apply_kernel(
    const unsigned int* __restrict__ pack, const unsigned int* __restrict__ phist,
    float* __restrict__ out, int P) {
    __shared__ float slut[NBINS * 32];   // 32 KB, bank-replicated LUT
    __shared__ unsigned int s[NBINS];
    __shared__ int sidx[NBINS];
    const int t = threadIdx.x;
    const int copy = t & 31;
    const int chan = blockIdx.x >> 2;    // BPC_A = 4

    // per-channel hist from BPC_H partials
    unsigned int h = 0;
    const unsigned int* pb = phist + (size_t)chan * BPC_H * NBINS;
    #pragma unroll
    for (int b = 0; b < BPC_H; ++b) h += pb[b * NBINS + t];
    s[t] = h;
    sidx[t] = (h != 0u) ? t : -1;
    __syncthreads();

    // max-reduce: last nonzero bin index
    for (int off = 128; off > 0; off >>= 1) {
        if (t < off) sidx[t] = max(sidx[t], sidx[t + off]);
        __syncthreads();
    }
    const int last_idx = sidx[0];
    const int last_val = (int)s[last_idx];
    const int step = (P - last_val) / 255;

    // Hillis-Steele inclusive scan
    for (int off = 1; off < NBINS; off <<= 1) {
        unsigned int v = (t >= off) ? s[t - off] : 0u;
        __syncthreads();
        s[t] += v;
        __syncthreads();
    }

    float lv;
    if (step == 0) {
        lv = (float)t;   // pass-through: identity LUT
    } else {
        int csp = (t == 0) ? 0 : (int)s[t - 1];
        lv = (float)min(max((csp + (step >> 1)) / step, 0), 255);
    }
    #pragma unroll
    for (int c = 0; c < 32; ++c)
        slut[t * 32 + ((t + c) & 31)] = lv;   // bank (t+c)&31: 2-way, free
    __syncthreads();

    const size_t basev = (size_t)blockIdx.x * NVEC_A;
    const unsigned int* pin = pack + basev;     // u8 pixels, L3-resident
    vfloat4* vout = (vfloat4*)out + basev;

    #pragma unroll 4
    for (int i = t; i < NVEC_A; i += 256) {
        unsigned int p = pin[i];
        vfloat4 r;
        r.x = slut[(p & 255u) * 32 + copy];
        r.y = slut[((p >> 8) & 255u) * 32 + copy];
        r.z = slut[((p >> 16) & 255u) * 32 + copy];
        r.w = slut[(p >> 24) * 32 + copy];
        __builtin_nontemporal_store(r, &vout[i]);
    }
}

extern "C" void kernel_launch(void* const* d_in, const int* in_sizes, int n_in,
                              void* d_out, int out_size, void* d_ws, size_t ws_size,
                              hipStream_t stream) {
    const float* img = (const float*)d_in[0];
    float* out = (float*)d_out;

    const int P = 512 * 512;        // pixels per channel
    const int total = in_sizes[0];  // 64*3*512*512 elements
    const int N = total / P;        // 192 channels

    // ws layout: packed u8 pixels (total bytes) | partial hists (3 MB)
    unsigned int* pack  = (unsigned int*)d_ws;
    unsigned int* phist = (unsigned int*)((char*)d_ws + (size_t)total);

    eq_hist_pack_kernel<<<N * BPC_H, 256, 0, stream>>>(img, pack, phist);
    eq_lut_apply_kernel<<<N * BPC_A, 256, 0, stream>>>(pack, phist, out, P);
}